// Round 1
// baseline (244.125 us; speedup 1.0000x reference)
//
#include <hip/hip_runtime.h>

#define BB   8192   // batch (M)
#define DIN  4096   // K
#define DOUT 2048   // N

typedef unsigned short ushort_t;
typedef __attribute__((ext_vector_type(8))) short bf16x8;   // 8 bf16 (4 VGPRs)
typedef __attribute__((ext_vector_type(4))) float f32x4;    // 4 fp32 acc

// round-to-nearest-even fp32 -> bf16 bits
__device__ inline ushort_t f2bf(float f) {
    union { float f; unsigned u; } v; v.f = f;
    unsigned u = v.u;
    return (ushort_t)((u + 0x7fffu + ((u >> 16) & 1u)) >> 16);
}

// async global->LDS, 16B per lane; LDS dest must be wave-uniform base (lane*16 implicit)
#define GLOAD16(g, s)                                                        \
    __builtin_amdgcn_global_load_lds(                                        \
        (const __attribute__((address_space(1))) void*)(g),                  \
        (__attribute__((address_space(3))) void*)(s), 16, 0, 0)

// ---------------- pre-pass 1: inputs fp32 -> bf16 ----------------
struct __align__(8) us4 { ushort_t x, y, z, w; };

__global__ __launch_bounds__(256) void convA(const float4* __restrict__ in,
                                             us4* __restrict__ out, int n4) {
    int i = blockIdx.x * blockDim.x + threadIdx.x;
    int stride = gridDim.x * blockDim.x;
    for (; i < n4; i += stride) {
        float4 v = in[i];
        us4 o;
        o.x = f2bf(v.x); o.y = f2bf(v.y); o.z = f2bf(v.z); o.w = f2bf(v.w);
        out[i] = o;
    }
}

// ---------------- pre-pass 2: WT[n][k] = bf16(kernel[k][n]*map[k][n]) ----------------
__global__ __launch_bounds__(256) void maskT(const float* __restrict__ Kn,
                                             const float* __restrict__ Mp,
                                             ushort_t* __restrict__ WT) {
    __shared__ ushort_t t[32][33];   // +1 pad: conflict-free transpose
    const int n0 = blockIdx.x * 32;
    const int k0 = blockIdx.y * 32;
    const int tx = threadIdx.x, ty = threadIdx.y;
    #pragma unroll
    for (int i = ty; i < 32; i += 8) {
        size_t idx = (size_t)(k0 + i) * DOUT + (n0 + tx);
        t[i][tx] = f2bf(Kn[idx] * Mp[idx]);
    }
    __syncthreads();
    #pragma unroll
    for (int i = ty; i < 32; i += 8) {
        WT[(size_t)(n0 + i) * DIN + (k0 + tx)] = t[tx][i];
    }
}

// ---------------- main GEMM: C = A(bf16) * WT^T(bf16) + bias ----------------
// m97 structure: 128x128 tile, BK=32, 4 waves (2x2), 16x16x32 bf16 MFMA,
// global_load_lds width=16 staging, 2 barriers per K-step.
__global__ __launch_bounds__(256) void sgemm_bf16(const ushort_t* __restrict__ A,   // [M][K]
                                                  const ushort_t* __restrict__ BT,  // [N][K]
                                                  const float* __restrict__ bias,   // [N]
                                                  float* __restrict__ C) {          // [M][N]
    constexpr int K = DIN, N = DOUT;
    constexpr int BM = 128, BN = 128, BK = 32;
    __shared__ ushort_t As[BM * BK];
    __shared__ ushort_t Bs[BN * BK];

    const int tid  = threadIdx.x;
    const int lane = tid & 63;
    const int w    = tid >> 6;     // wave 0..3
    const int wr   = w >> 1;       // wave row (0..1)
    const int wc   = w & 1;        // wave col (0..1)

    const int m0 = blockIdx.y * BM;
    const int n0 = blockIdx.x * BN;

    // staging: each wave covers 16 rows per issue; 4 lanes x 16B per row (32 bf16)
    const int srow  = w * 16 + (lane >> 2);
    const int skoff = (lane & 3) * 8;

    const ushort_t* Ag0 = A  + (size_t)(m0 + srow) * K + skoff;
    const ushort_t* Ag1 = A  + (size_t)(m0 + 64 + srow) * K + skoff;
    const ushort_t* Bg0 = BT + (size_t)(n0 + srow) * K + skoff;
    const ushort_t* Bg1 = BT + (size_t)(n0 + 64 + srow) * K + skoff;

    ushort_t* As0 = &As[(w * 16) * BK];        // wave-uniform LDS bases
    ushort_t* As1 = &As[(64 + w * 16) * BK];
    ushort_t* Bs0 = &Bs[(w * 16) * BK];
    ushort_t* Bs1 = &Bs[(64 + w * 16) * BK];

    const int arow = wr * 64 + (lane & 15);
    const int brow = wc * 64 + (lane & 15);
    const int k8   = (lane >> 4) * 8;

    f32x4 acc[4][4];
    #pragma unroll
    for (int m = 0; m < 4; ++m)
        #pragma unroll
        for (int n = 0; n < 4; ++n)
            acc[m][n] = (f32x4){0.f, 0.f, 0.f, 0.f};

    for (int kt = 0; kt < K; kt += BK) {
        GLOAD16(Ag0 + kt, As0);
        GLOAD16(Ag1 + kt, As1);
        GLOAD16(Bg0 + kt, Bs0);
        GLOAD16(Bg1 + kt, Bs1);
        __syncthreads();   // drains vmcnt; staging visible to all waves

        bf16x8 af[4], bfr[4];
        #pragma unroll
        for (int m = 0; m < 4; ++m)
            af[m] = *(const bf16x8*)&As[(arow + m * 16) * BK + k8];
        #pragma unroll
        for (int n = 0; n < 4; ++n)
            bfr[n] = *(const bf16x8*)&Bs[(brow + n * 16) * BK + k8];

        #pragma unroll
        for (int m = 0; m < 4; ++m)
            #pragma unroll
            for (int n = 0; n < 4; ++n)
                acc[m][n] = __builtin_amdgcn_mfma_f32_16x16x32_bf16(af[m], bfr[n], acc[m][n], 0, 0, 0);
        __syncthreads();   // reads done before next stage overwrites
    }

    // epilogue: C/D layout col=lane&15, row=(lane>>4)*4+j  [m89-verified]
    #pragma unroll
    for (int n = 0; n < 4; ++n) {
        const int col = n0 + wc * 64 + n * 16 + (lane & 15);
        const float bv = bias[col];
        #pragma unroll
        for (int m = 0; m < 4; ++m) {
            const int row0 = m0 + wr * 64 + m * 16 + (lane >> 4) * 4;
            #pragma unroll
            for (int j = 0; j < 4; ++j)
                C[(size_t)(row0 + j) * N + col] = acc[m][n][j] + bv;
        }
    }
}

// ---------------- fallback (ws too small): fp32 LDS-tiled GEMM ----------------
__global__ __launch_bounds__(1024) void gemm_fb(const float* __restrict__ A,
                                                const float* __restrict__ Kn,
                                                const float* __restrict__ Mp,
                                                const float* __restrict__ bias,
                                                float* __restrict__ C) {
    __shared__ float As[32][33];
    __shared__ float Bs[32][33];
    const int tx = threadIdx.x, ty = threadIdx.y;
    const int row = blockIdx.y * 32 + ty;
    const int col = blockIdx.x * 32 + tx;
    float acc = 0.f;
    for (int kt = 0; kt < DIN; kt += 32) {
        As[ty][tx] = A[(size_t)row * DIN + kt + tx];
        size_t bidx = (size_t)(kt + ty) * DOUT + col;
        Bs[ty][tx] = Kn[bidx] * Mp[bidx];
        __syncthreads();
        #pragma unroll
        for (int kk = 0; kk < 32; ++kk)
            acc += As[ty][kk] * Bs[kk][tx];
        __syncthreads();
    }
    C[(size_t)row * DOUT + col] = acc + bias[col];
}

extern "C" void kernel_launch(void* const* d_in, const int* in_sizes, int n_in,
                              void* d_out, int out_size, void* d_ws, size_t ws_size,
                              hipStream_t stream) {
    const float* inputs = (const float*)d_in[0];   // [8192,4096]
    const float* kernel = (const float*)d_in[1];   // [4096,2048]
    const float* bias   = (const float*)d_in[2];   // [2048]
    const float* map    = (const float*)d_in[3];   // [4096,2048]
    float* out = (float*)d_out;                    // [8192,2048]

    const size_t abytes = (size_t)BB * DIN * sizeof(ushort_t);   // 64 MiB
    const size_t wbytes = (size_t)DIN * DOUT * sizeof(ushort_t); // 16 MiB

    if (ws_size >= abytes + wbytes) {
        ushort_t* Abf = (ushort_t*)d_ws;
        ushort_t* WT  = (ushort_t*)((char*)d_ws + abytes);

        convA<<<2048, 256, 0, stream>>>((const float4*)inputs, (us4*)Abf,
                                        (int)((size_t)BB * DIN / 4));
        maskT<<<dim3(DOUT / 32, DIN / 32), dim3(32, 8), 0, stream>>>(kernel, map, WT);
        sgemm_bf16<<<dim3(DOUT / 128, BB / 128), 256, 0, stream>>>(Abf, WT, bias, out);
    } else {
        gemm_fb<<<dim3(DOUT / 32, BB / 32), dim3(32, 32), 0, stream>>>(inputs, kernel, map,
                                                                       bias, out);
    }
}

// Round 2
// 175.847 us; speedup vs baseline: 1.3883x; 1.3883x over previous
//
#include <hip/hip_runtime.h>

#define BB   8192   // batch (M)
#define DIN  4096   // K
#define DOUT 2048   // N

typedef unsigned short ushort_t;
typedef __attribute__((ext_vector_type(8))) short bf16x8;   // 8 bf16 (4 VGPRs)
typedef __attribute__((ext_vector_type(4))) float f32x4;    // 4 fp32 acc

// round-to-nearest-even fp32 -> bf16 bits
__device__ inline ushort_t f2bf(float f) {
    union { float f; unsigned u; } v; v.f = f;
    unsigned u = v.u;
    return (ushort_t)((u + 0x7fffu + ((u >> 16) & 1u)) >> 16);
}

// async global->LDS, 16B per lane; LDS dest = wave-uniform base (+lane*16 implicit)
#define GLOAD16(g, s)                                                        \
    __builtin_amdgcn_global_load_lds(                                        \
        (const __attribute__((address_space(1))) void*)(g),                  \
        (__attribute__((address_space(3))) void*)(s), 16, 0, 0)

#define FENCE() asm volatile("" ::: "memory")
#define BAR()   do { FENCE(); __builtin_amdgcn_s_barrier(); FENCE(); } while (0)
#define VMCNT(n) asm volatile("s_waitcnt vmcnt(" #n ")" ::: "memory")

// ---------------- pre-pass 1: inputs fp32 -> bf16 ----------------
struct __align__(8) us4 { ushort_t x, y, z, w; };

__global__ __launch_bounds__(256) void convA(const float4* __restrict__ in,
                                             us4* __restrict__ out, int n4) {
    int i = blockIdx.x * blockDim.x + threadIdx.x;
    int stride = gridDim.x * blockDim.x;
    for (; i < n4; i += stride) {
        float4 v = in[i];
        us4 o;
        o.x = f2bf(v.x); o.y = f2bf(v.y); o.z = f2bf(v.z); o.w = f2bf(v.w);
        out[i] = o;
    }
}

// ---------------- pre-pass 2: WT[n][k] = bf16(kernel[k][n]*map[k][n]) ----------------
__global__ __launch_bounds__(256) void maskT(const float* __restrict__ Kn,
                                             const float* __restrict__ Mp,
                                             ushort_t* __restrict__ WT) {
    __shared__ ushort_t t[32][33];
    const int n0 = blockIdx.x * 32;
    const int k0 = blockIdx.y * 32;
    const int tx = threadIdx.x, ty = threadIdx.y;
    #pragma unroll
    for (int i = ty; i < 32; i += 8) {
        size_t idx = (size_t)(k0 + i) * DOUT + (n0 + tx);
        t[i][tx] = f2bf(Kn[idx] * Mp[idx]);
    }
    __syncthreads();
    #pragma unroll
    for (int i = ty; i < 32; i += 8) {
        WT[(size_t)(n0 + i) * DIN + (k0 + tx)] = t[tx][i];
    }
}

// ---------------- main GEMM: 256x256 tile, BK=64, 8 waves, 4-phase counted-vmcnt ----
// LDS (dynamic, 128 KiB): buf d (64 KiB each):
//   A half h: d*65536 + h*16384   ([128 rows][64 cols] bf16, row=128B)
//   B half h: d*65536 + 32768 + h*16384
// st_16x32 swizzle: element linear lin=r*128+c*2 stored at lin ^ (((lin>>9)&1)<<5).
// gload_lds dest linear; inverse swizzle applied to per-lane GLOBAL source (rule 21).
__global__ __launch_bounds__(512) void gemm8(const ushort_t* __restrict__ A,   // [M][K] bf16
                                             const ushort_t* __restrict__ BT,  // [N][K] bf16
                                             const float* __restrict__ bias,   // [N]
                                             float* __restrict__ C) {          // [M][N] f32
    constexpr int K = DIN, N = DOUT;
    constexpr int NT = K / 64;           // 64 K-tiles
    extern __shared__ char sb[];         // 128 KiB

    const int tid  = threadIdx.x;
    const int lane = tid & 63;
    const int w    = tid >> 6;           // wave 0..7
    const int wr   = w >> 2;             // 0..1  (M half)
    const int wcn  = w & 3;              // 0..3  (N quarter)
    const int l15  = lane & 15;

    // bijective XCD swizzle: grid = 8 x 32 = 256 blocks, 256 % 8 == 0
    const int orig = blockIdx.y * 8 + blockIdx.x;
    const int swz  = (orig & 7) * 32 + (orig >> 3);
    const int n0   = (swz & 7) * 256;    // N tile
    const int m0   = (swz >> 3) * 256;   // M tile

    // ---- staging source (inverse-swizzled global addr), chunk (h,c): rows c*8.. ----
    const int srow = lane >> 3;                                  // 0..7 in chunk
    const int scol = ((lane & 7) * 8) ^ ((lane & 32) ? 16 : 0);  // swizzled col
    const ushort_t* Ab = A  + (size_t)(m0 + srow) * K + scol;
    const ushort_t* Bb = BT + (size_t)(n0 + srow) * K + scol;

    auto stgA = [&](int buf, int kt, int h, int c) {
        GLOAD16(Ab + (size_t)(h * 128 + c * 8) * K + kt * 64,
                sb + buf * 65536 + h * 16384 + c * 1024);
    };
    auto stgB = [&](int buf, int kt, int h, int c) {
        GLOAD16(Bb + (size_t)(h * 128 + c * 8) * K + kt * 64,
                sb + buf * 65536 + 32768 + h * 16384 + c * 1024);
    };

    // ---- fragment ds_read offset (swizzle folds to constant per-lane XOR-32) ----
    const int fswz = (l15 & 4) ? 32 : 0;
    const int foff = l15 * 128 + (((lane >> 4) * 16) ^ fswz);

    f32x4 acc[8][4] = {};   // 8 m-frags x 4 n-frags
    bf16x8 bf[4][2];        // B frags: n x ks, live across the 4 phases of a tile

    // ---- prologue: stage tile 0 into buf 0; per-thread order B0,B0,B1,B1,AL0,AL0,AL1,AL1
    stgB(0, 0, 0, w); stgB(0, 0, 0, 8 + w);
    stgB(0, 0, 1, w); stgB(0, 0, 1, 8 + w);
    stgA(0, 0, 0, w); stgA(0, 0, 1, w);          // A rows 0-63 (both halves)
    stgA(0, 0, 0, 8 + w); stgA(0, 0, 1, 8 + w);  // A rows 64-127
    VMCNT(2);   // first 6 landed: B full + A rows 0-63
    BAR();

    for (int t = 0; t < NT; ++t) {
        const int  cur = t & 1;
        const int  nxt = cur ^ 1;
        const bool pf  = (t + 1 < NT);
        const char* Abase = sb + cur * 65536 + wr * 16384;
        const char* Bbase = sb + cur * 65536 + 32768 + (wcn >> 1) * 16384 + (wcn & 1) * 8192;

        #pragma unroll
        for (int q = 0; q < 4; ++q) {
            // -- ds reads for this quadrant (A rows [32q,32q+32), + all B at q0)
            bf16x8 af[2][2];
            #pragma unroll
            for (int mm = 0; mm < 2; ++mm)
                #pragma unroll
                for (int ks = 0; ks < 2; ++ks)
                    af[mm][ks] = *(const bf16x8*)(Abase + (2 * q + mm) * 2048 + ks * 64 + foff);
            if (q == 0) {
                #pragma unroll
                for (int n = 0; n < 4; ++n)
                    #pragma unroll
                    for (int ks = 0; ks < 2; ++ks)
                        bf[n][ks] = *(const bf16x8*)(Bbase + n * 2048 + ks * 64 + foff);
            }
            // -- stage one half-tile of tile t+1 into buf nxt (dead since tile t-1)
            if (pf) {
                if      (q == 0) { stgB(nxt, t + 1, 0, w); stgB(nxt, t + 1, 0, 8 + w); }
                else if (q == 1) { stgB(nxt, t + 1, 1, w); stgB(nxt, t + 1, 1, 8 + w); }
                else if (q == 2) { stgA(nxt, t + 1, 0, w); stgA(nxt, t + 1, 1, w); }
                else             { stgA(nxt, t + 1, 0, 8 + w); stgA(nxt, t + 1, 1, 8 + w); }
            }
            BAR();   // all waves issued loads; frag data deps handled by compiler lgkm waits
            __builtin_amdgcn_s_setprio(1);
            #pragma unroll
            for (int ks = 0; ks < 2; ++ks)
                #pragma unroll
                for (int mm = 0; mm < 2; ++mm)
                    #pragma unroll
                    for (int n = 0; n < 4; ++n)
                        acc[2 * q + mm][n] = __builtin_amdgcn_mfma_f32_16x16x32_bf16(
                            af[mm][ks], bf[n][ks], acc[2 * q + mm][n], 0, 0, 0);
            __builtin_amdgcn_s_setprio(0);
            // -- counted vmcnt, always before a barrier so retirement propagates
            if (q == 1) {
                if (pf) { VMCNT(4); }   // tile t A-high landed (4 newest = next-tile B)
                else    { VMCNT(0); }   // last tile: drain
            }
            if (q == 3 && pf) { VMCNT(2); }  // next tile's B + A-low landed
            BAR();
        }
    }

    // ---- epilogue: C/D layout col=lane&15, row=(lane>>4)*4+j; fused bias ----
    #pragma unroll
    for (int n = 0; n < 4; ++n) {
        const int col = n0 + wcn * 64 + n * 16 + l15;
        const float bv = bias[col];
        #pragma unroll
        for (int m = 0; m < 8; ++m) {
            const int r0 = m0 + wr * 128 + m * 16 + (lane >> 4) * 4;
            #pragma unroll
            for (int j = 0; j < 4; ++j)
                C[(size_t)(r0 + j) * N + col] = acc[m][n][j] + bv;
        }
    }
}

// ---------------- fallback (ws too small): fp32 LDS-tiled GEMM ----------------
__global__ __launch_bounds__(1024) void gemm_fb(const float* __restrict__ A,
                                                const float* __restrict__ Kn,
                                                const float* __restrict__ Mp,
                                                const float* __restrict__ bias,
                                                float* __restrict__ C) {
    __shared__ float As[32][33];
    __shared__ float Bs[32][33];
    const int tx = threadIdx.x, ty = threadIdx.y;
    const int row = blockIdx.y * 32 + ty;
    const int col = blockIdx.x * 32 + tx;
    float acc = 0.f;
    for (int kt = 0; kt < DIN; kt += 32) {
        As[ty][tx] = A[(size_t)row * DIN + kt + tx];
        size_t bidx = (size_t)(kt + ty) * DOUT + col;
        Bs[ty][tx] = Kn[bidx] * Mp[bidx];
        __syncthreads();
        #pragma unroll
        for (int kk = 0; kk < 32; ++kk)
            acc += As[ty][kk] * Bs[kk][tx];
        __syncthreads();
    }
    C[(size_t)row * DOUT + col] = acc + bias[col];
}

extern "C" void kernel_launch(void* const* d_in, const int* in_sizes, int n_in,
                              void* d_out, int out_size, void* d_ws, size_t ws_size,
                              hipStream_t stream) {
    const float* inputs = (const float*)d_in[0];   // [8192,4096]
    const float* kernel = (const float*)d_in[1];   // [4096,2048]
    const float* bias   = (const float*)d_in[2];   // [2048]
    const float* map    = (const float*)d_in[3];   // [4096,2048]
    float* out = (float*)d_out;                    // [8192,2048]

    const size_t abytes = (size_t)BB * DIN * sizeof(ushort_t);   // 64 MiB
    const size_t wbytes = (size_t)DIN * DOUT * sizeof(ushort_t); // 16 MiB

    if (ws_size >= abytes + wbytes) {
        ushort_t* Abf = (ushort_t*)d_ws;
        ushort_t* WT  = (ushort_t*)((char*)d_ws + abytes);

        static bool attr_set = false;
        if (!attr_set) {
            hipFuncSetAttribute((const void*)gemm8,
                                hipFuncAttributeMaxDynamicSharedMemorySize, 131072);
            attr_set = true;
        }

        convA<<<2048, 256, 0, stream>>>((const float4*)inputs, (us4*)Abf,
                                        (int)((size_t)BB * DIN / 4));
        maskT<<<dim3(DOUT / 32, DIN / 32), dim3(32, 8), 0, stream>>>(kernel, map, WT);
        gemm8<<<dim3(DOUT / 256, BB / 256), 512, 131072, stream>>>(Abf, WT, bias, out);
    } else {
        gemm_fb<<<dim3(DOUT / 32, BB / 32), dim3(32, 32), 0, stream>>>(inputs, kernel, map,
                                                                       bias, out);
    }
}

// Round 3
// 162.838 us; speedup vs baseline: 1.4992x; 1.0799x over previous
//
#include <hip/hip_runtime.h>

#define BB   8192   // batch (M)
#define DIN  4096   // K
#define DOUT 2048   // N

typedef unsigned short ushort_t;
typedef __attribute__((ext_vector_type(8))) short bf16x8;   // 8 bf16 (4 VGPRs)
typedef __attribute__((ext_vector_type(4))) float f32x4;    // 4 fp32 acc

// round-to-nearest-even fp32 -> bf16 bits
__device__ inline ushort_t f2bf(float f) {
    union { float f; unsigned u; } v; v.f = f;
    unsigned u = v.u;
    return (ushort_t)((u + 0x7fffu + ((u >> 16) & 1u)) >> 16);
}

// async global->LDS, 16B per lane; LDS dest = wave-uniform base (+lane*16 implicit)
#define GLOAD16(g, s)                                                        \
    __builtin_amdgcn_global_load_lds(                                        \
        (const __attribute__((address_space(1))) void*)(g),                  \
        (__attribute__((address_space(3))) void*)(s), 16, 0, 0)

#define FENCE() asm volatile("" ::: "memory")
#define BAR()   do { FENCE(); __builtin_amdgcn_s_barrier(); FENCE(); } while (0)
#define VMCNT(n) asm volatile("s_waitcnt vmcnt(" #n ")" ::: "memory")

// ---------------- pre-pass 1: inputs fp32 -> bf16 ----------------
struct __align__(8) us4 { ushort_t x, y, z, w; };

__global__ __launch_bounds__(256) void convA(const float4* __restrict__ in,
                                             us4* __restrict__ out, int n4) {
    int i = blockIdx.x * blockDim.x + threadIdx.x;
    int stride = gridDim.x * blockDim.x;
    for (; i < n4; i += stride) {
        float4 v = in[i];
        us4 o;
        o.x = f2bf(v.x); o.y = f2bf(v.y); o.z = f2bf(v.z); o.w = f2bf(v.w);
        out[i] = o;
    }
}

// ---------------- pre-pass 2: WT[n][k] = bf16(kernel[k][n]*map[k][n]) ----------------
__global__ __launch_bounds__(256) void maskT(const float* __restrict__ Kn,
                                             const float* __restrict__ Mp,
                                             ushort_t* __restrict__ WT) {
    __shared__ ushort_t t[32][33];
    const int n0 = blockIdx.x * 32;
    const int k0 = blockIdx.y * 32;
    const int tx = threadIdx.x, ty = threadIdx.y;
    #pragma unroll
    for (int i = ty; i < 32; i += 8) {
        size_t idx = (size_t)(k0 + i) * DOUT + (n0 + tx);
        t[i][tx] = f2bf(Kn[idx] * Mp[idx]);
    }
    __syncthreads();
    #pragma unroll
    for (int i = ty; i < 32; i += 8) {
        WT[(size_t)(n0 + i) * DIN + (k0 + tx)] = t[tx][i];
    }
}

// ---------------- main GEMM: 256x256 tile, BK=64, 8 waves, 4-phase counted-vmcnt ----
// LDS (dynamic, 128 KiB): buf d (64 KiB each):
//   A half h: d*65536 + h*16384   ([128 rows][64 cols] bf16, row=128B)
//   B half h: d*65536 + 32768 + h*16384
// Bank swizzle (G4, 128B-stride tile): byte_col ^= (row&7)<<4. Applied as
// inverse-permuted GLOBAL source (gload_lds dest stays linear, rule 21) +
// the same XOR on the frag ds_read column. Staging chunks are 8-row aligned
// and all frag row offsets are multiples of 16, so row&7 == (lane-derived).
__global__ __launch_bounds__(512) void gemm8(const ushort_t* __restrict__ A,   // [M][K] bf16
                                             const ushort_t* __restrict__ BT,  // [N][K] bf16
                                             const float* __restrict__ bias,   // [N]
                                             float* __restrict__ C) {          // [M][N] f32
    constexpr int K = DIN, N = DOUT;
    constexpr int NT = K / 64;           // 64 K-tiles
    extern __shared__ char sb[];         // 128 KiB

    const int tid  = threadIdx.x;
    const int lane = tid & 63;
    const int w    = tid >> 6;           // wave 0..7
    const int wr   = w >> 2;             // 0..1  (M half)
    const int wcn  = w & 3;              // 0..3  (N quarter)
    const int l15  = lane & 15;

    // bijective XCD swizzle: grid = 8 x 32 = 256 blocks, 256 % 8 == 0
    const int orig = blockIdx.y * 8 + blockIdx.x;
    const int swz  = (orig & 7) * 32 + (orig >> 3);
    const int n0   = (swz & 7) * 256;    // N tile
    const int m0   = (swz >> 3) * 256;   // M tile

    // ---- staging source: chunk (h,c) = rows c*8..c*8+7 of half h ----
    // LDS slot for lane l: row c*8 + (l>>3), col16unit (l&7). Pre-apply the
    // inverse swizzle to the GLOBAL column: col16unit = (l&7) ^ (l>>3).
    const int srow = lane >> 3;                         // 0..7 within chunk
    const int scol = ((lane & 7) ^ srow) * 8;           // bf16 elements
    const ushort_t* Ab = A  + (size_t)(m0 + srow) * K + scol;
    const ushort_t* Bb = BT + (size_t)(n0 + srow) * K + scol;

    auto stgA = [&](int buf, int kt, int h, int c) {
        GLOAD16(Ab + (size_t)(h * 128 + c * 8) * K + kt * 64,
                sb + buf * 65536 + h * 16384 + c * 1024);
    };
    auto stgB = [&](int buf, int kt, int h, int c) {
        GLOAD16(Bb + (size_t)(h * 128 + c * 8) * K + kt * 64,
                sb + buf * 65536 + 32768 + h * 16384 + c * 1024);
    };

    // ---- fragment ds_read: row = <mult of 16> + l15 -> row&7 = l15&7 ----
    const int fxor = (l15 & 7) << 4;     // swizzle XOR on byte column
    const int kq   = (lane >> 4) * 16;   // 16B col within K-half

    f32x4 acc[8][4] = {};   // 8 m-frags x 4 n-frags
    bf16x8 bf[4][2];        // B frags: n x ks, live across the 4 phases of a tile

    // ---- prologue: stage tile 0 into buf 0; per-thread order B0,B0,B1,B1,AL,AL,AH,AH
    stgB(0, 0, 0, w); stgB(0, 0, 0, 8 + w);
    stgB(0, 0, 1, w); stgB(0, 0, 1, 8 + w);
    stgA(0, 0, 0, w); stgA(0, 0, 1, w);          // A rows 0-63 (both halves)
    stgA(0, 0, 0, 8 + w); stgA(0, 0, 1, 8 + w);  // A rows 64-127
    VMCNT(2);   // first 6 landed: B full + A rows 0-63
    BAR();

    for (int t = 0; t < NT; ++t) {
        const int  cur = t & 1;
        const int  nxt = cur ^ 1;
        const bool pf  = (t + 1 < NT);
        const char* Abase = sb + cur * 65536 + wr * 16384;
        const char* Bbase = sb + cur * 65536 + 32768 + (wcn >> 1) * 16384 + (wcn & 1) * 8192;

        #pragma unroll
        for (int q = 0; q < 4; ++q) {
            // -- ds reads for this quadrant (A rows [32q,32q+32), + all B at q0)
            bf16x8 af[2][2];
            #pragma unroll
            for (int mm = 0; mm < 2; ++mm)
                #pragma unroll
                for (int ks = 0; ks < 2; ++ks)
                    af[mm][ks] = *(const bf16x8*)(Abase + (2 * q + mm) * 2048 + l15 * 128 +
                                                  ((ks * 64 + kq) ^ fxor));
            if (q == 0) {
                #pragma unroll
                for (int n = 0; n < 4; ++n)
                    #pragma unroll
                    for (int ks = 0; ks < 2; ++ks)
                        bf[n][ks] = *(const bf16x8*)(Bbase + n * 2048 + l15 * 128 +
                                                     ((ks * 64 + kq) ^ fxor));
            }
            // -- stage one half-tile of tile t+1 into buf nxt (dead since tile t-1)
            if (pf) {
                if      (q == 0) { stgB(nxt, t + 1, 0, w); stgB(nxt, t + 1, 0, 8 + w); }
                else if (q == 1) { stgB(nxt, t + 1, 1, w); stgB(nxt, t + 1, 1, 8 + w); }
                else if (q == 2) { stgA(nxt, t + 1, 0, w); stgA(nxt, t + 1, 1, w); }
                else             { stgA(nxt, t + 1, 0, 8 + w); stgA(nxt, t + 1, 1, 8 + w); }
            }
            BAR();   // all waves issued loads; frag data deps handled by compiler lgkm waits
            __builtin_amdgcn_s_setprio(1);
            #pragma unroll
            for (int ks = 0; ks < 2; ++ks)
                #pragma unroll
                for (int mm = 0; mm < 2; ++mm)
                    #pragma unroll
                    for (int n = 0; n < 4; ++n)
                        acc[2 * q + mm][n] = __builtin_amdgcn_mfma_f32_16x16x32_bf16(
                            af[mm][ks], bf[n][ks], acc[2 * q + mm][n], 0, 0, 0);
            __builtin_amdgcn_s_setprio(0);
            // -- counted vmcnt, always before a barrier so retirement propagates
            if (q == 1) {
                if (pf) { VMCNT(4); }   // tile t A-high landed (4 newest = next-tile B)
                else    { VMCNT(0); }   // last tile: drain
            }
            if (q == 3 && pf) { VMCNT(2); }  // next tile's B + A-low landed
            BAR();
        }
    }

    // ---- epilogue: C/D layout col=lane&15, row=(lane>>4)*4+j; fused bias ----
    #pragma unroll
    for (int n = 0; n < 4; ++n) {
        const int col = n0 + wcn * 64 + n * 16 + l15;
        const float bv = bias[col];
        #pragma unroll
        for (int m = 0; m < 8; ++m) {
            const int r0 = m0 + wr * 128 + m * 16 + (lane >> 4) * 4;
            #pragma unroll
            for (int j = 0; j < 4; ++j)
                C[(size_t)(r0 + j) * N + col] = acc[m][n][j] + bv;
        }
    }
}

// ---------------- fallback (ws too small): fp32 LDS-tiled GEMM ----------------
__global__ __launch_bounds__(1024) void gemm_fb(const float* __restrict__ A,
                                                const float* __restrict__ Kn,
                                                const float* __restrict__ Mp,
                                                const float* __restrict__ bias,
                                                float* __restrict__ C) {
    __shared__ float As[32][33];
    __shared__ float Bs[32][33];
    const int tx = threadIdx.x, ty = threadIdx.y;
    const int row = blockIdx.y * 32 + ty;
    const int col = blockIdx.x * 32 + tx;
    float acc = 0.f;
    for (int kt = 0; kt < DIN; kt += 32) {
        As[ty][tx] = A[(size_t)row * DIN + kt + tx];
        size_t bidx = (size_t)(kt + ty) * DOUT + col;
        Bs[ty][tx] = Kn[bidx] * Mp[bidx];
        __syncthreads();
        #pragma unroll
        for (int kk = 0; kk < 32; ++kk)
            acc += As[ty][kk] * Bs[kk][tx];
        __syncthreads();
    }
    C[(size_t)row * DOUT + col] = acc + bias[col];
}

extern "C" void kernel_launch(void* const* d_in, const int* in_sizes, int n_in,
                              void* d_out, int out_size, void* d_ws, size_t ws_size,
                              hipStream_t stream) {
    const float* inputs = (const float*)d_in[0];   // [8192,4096]
    const float* kernel = (const float*)d_in[1];   // [4096,2048]
    const float* bias   = (const float*)d_in[2];   // [2048]
    const float* map    = (const float*)d_in[3];   // [4096,2048]
    float* out = (float*)d_out;                    // [8192,2048]

    const size_t abytes = (size_t)BB * DIN * sizeof(ushort_t);   // 64 MiB
    const size_t wbytes = (size_t)DIN * DOUT * sizeof(ushort_t); // 16 MiB

    if (ws_size >= abytes + wbytes) {
        ushort_t* Abf = (ushort_t*)d_ws;
        ushort_t* WT  = (ushort_t*)((char*)d_ws + abytes);

        static bool attr_set = false;
        if (!attr_set) {
            hipFuncSetAttribute((const void*)gemm8,
                                hipFuncAttributeMaxDynamicSharedMemorySize, 131072);
            attr_set = true;
        }

        convA<<<2048, 256, 0, stream>>>((const float4*)inputs, (us4*)Abf,
                                        (int)((size_t)BB * DIN / 4));
        maskT<<<dim3(DOUT / 32, DIN / 32), dim3(32, 8), 0, stream>>>(kernel, map, WT);
        gemm8<<<dim3(DOUT / 256, BB / 256), 512, 131072, stream>>>(Abf, WT, bias, out);
    } else {
        gemm_fb<<<dim3(DOUT / 32, BB / 32), dim3(32, 32), 0, stream>>>(inputs, kernel, map,
                                                                       bias, out);
    }
}